// Round 10
// baseline (43.833 us; speedup 1.0000x reference)
//
#include <hip/hip_runtime.h>
#include <math.h>

#define NKP 133
#define NROWS (256 * NKP)            // 34048 rows of 1024
#define RH_TOTAL (2 * NROWS)         // 68096 row-halves of 512
#define NQUADS (RH_TOTAL / 4)        // 17024 quads (4 row-halves each)
#define NBLOCKS 2048
#define NWAVES (NBLOCKS * 4)         // 8192: ~2.08 quads/wave
#define C2P  14.4269504088896f       // 10*log2(e): exp(10x)=exp2(C2P*x)
#define NK2  0.02251706f             // log2(e)/(2*5.66^2)
#define RAD  16.98f                  // 5.66*3
#define LN2f 0.69314718055994531f
#define WTAPS 5                      // 5*16 = 80-wide window (covers |d|<=35 + clamps)

static __device__ __forceinline__ float fexp2(float x) { return __builtin_amdgcn_exp2f(x); }
static __device__ __forceinline__ float frcp (float x) { return __builtin_amdgcn_rcpf(x); }

__global__ __launch_bounds__(256) void rtmcc_kernel(
    const float* __restrict__ pred,       // [RH_TOTAL][512]
    const float* __restrict__ keypoints,  // [NROWS][3]
    float* __restrict__ out)              // [1], zeroed by memset in-graph
{
    const int wave = threadIdx.x >> 6;
    const int lane = threadIdx.x & 63;
    const int g    = lane >> 4;           // 16-lane group -> one row-half
    const int l4   = lane & 15;
    const int gh   = g >> 1;              // row within quad pair
    const int h    = g & 1;               // half: 0=x, 1=y
    __shared__ float2 twb[256];           // (e-1, e*g) at d=t-128; zero |d|>35
    __shared__ float lds[4];

    float acc = 0.0f;
    int q = blockIdx.x * 4 + wave;        // first quad for this wave

    // rolling keypoint prefetch (issues before table build; latency hidden)
    float kx, ky, kv;
    {
        const int row = 2 * q + gh;
        kx = keypoints[row * 3 + 0];
        ky = keypoints[row * 3 + 1];
        kv = keypoints[row * 3 + 2];
    }

    {   // window table once per block
        const int t = threadIdx.x;
        const float d = (float)(t - 128);
        float em1 = 0.0f, eg = 0.0f;
        if (fabsf(d) <= 35.0f) {
            const float gg = fexp2(-d * d * NK2);   // gaussian target
            const float e  = fexp2(gg * C2P);       // exp(10*g)
            em1 = e - 1.0f; eg = e * gg;
        }
        twb[t] = make_float2(em1, eg);
    }
    __syncthreads();

    for (; q < NQUADS; q += NWAVES) {
        const float kxc = kx, kyc = ky, kvc = kv;
        const int qn = q + NWAVES;
        if (qn < NQUADS) {                // prefetch next iteration's keypoints
            const int rown = 2 * qn + gh;
            kx = keypoints[rown * 3 + 0];
            ky = keypoints[rown * 3 + 1];
            kv = keypoints[rown * 3 + 2];
        }

        const float mux = rintf(kxc * 2.0f);    // half-to-even = jnp.round
        const float muy = rintf(kyc * 2.0f);
        const bool oob = (mux - RAD >= 512.0f) || (muy - RAD >= 512.0f) ||
                         (mux + RAD + 1.0f < 0.0f) || (muy + RAD + 1.0f < 0.0f);
        const bool visible = (kvc >= 0.5f);
        const float w = (visible && oob) ? 0.0f : kvc;
        const bool act = (w > 0.0f);            // uniform within 16-lane group

        float S = 0.0f, Zw = 0.0f, R = 0.0f;
        if (act) {
            const float* ph = pred + (size_t)(4 * q + g) * 512;

            // ---- bulk: 8 float4 loads, column-interleaved (coalesced) ----
            float4 qv[8];
            #pragma unroll
            for (int v = 0; v < 8; ++v)
                qv[v] = *reinterpret_cast<const float4*>(ph + v * 64 + l4 * 4);

            float s0 = 0.f, s1 = 0.f, r0 = 0.f, r1 = 0.f;   // dual chains
            #pragma unroll
            for (int v = 0; v < 8; v += 2) {
                s0 += fexp2(C2P*qv[v].x)   + fexp2(C2P*qv[v].y)
                    + fexp2(C2P*qv[v].z)   + fexp2(C2P*qv[v].w);
                r0 -= (qv[v].x + qv[v].y) + (qv[v].z + qv[v].w);
                s1 += fexp2(C2P*qv[v+1].x) + fexp2(C2P*qv[v+1].y)
                    + fexp2(C2P*qv[v+1].z) + fexp2(C2P*qv[v+1].w);
                r1 -= (qv[v+1].x + qv[v+1].y) + (qv[v+1].z + qv[v+1].w);
            }
            S = s0 + s1; R = r0 + r1;

            // ---- window: 80 elems around mu, 5/lane, LDS table lookups ----
            // t = idx - mui + 128 provably in [48,208) for all mui in [0,512]
            const float mu = h ? muy : mux;
            const int mui = (int)mu;
            int ws = mui - 40; ws = ws < 0 ? 0 : (ws > 432 ? 432 : ws);
            #pragma unroll
            for (int v = 0; v < WTAPS; ++v) {
                const int idx = ws + l4 + v * 16;      // [ws, ws+80)
                const float pw = ph[idx];              // cache-hot re-read
                const float2 te = twb[idx - mui + 128];  // ds_read_b64, no clamp
                Zw += te.x;
                R  += te.y - te.x * pw;
            }
        }

        // ---- 4-step butterfly within each 16-lane group ----
        #pragma unroll
        for (int off = 1; off < 16; off <<= 1) {
            S  += __shfl_xor(S,  off, 64);
            Zw += __shfl_xor(Zw, off, 64);
            R  += __shfl_xor(R,  off, 64);
        }

        if (act) {
            const float Z = 512.0f + Zw;        // far-field e == 1.0f exactly
            acc += w * (10.0f * R * frcp(Z) + (__log2f(S) - __log2f(Z)) * LN2f);
        }
    }

    // each group's loss sits in all 16 of its lanes -> /16 exact
    acc *= (1.0f / (16.0f * 512.0f * 133.0f));
    #pragma unroll
    for (int off = 1; off < 64; off <<= 1) acc += __shfl_xor(acc, off, 64);
    if (lane == 0) lds[wave] = acc;
    __syncthreads();
    if (threadIdx.x == 0)
        atomicAdd(out, lds[0] + lds[1] + lds[2] + lds[3]);   // 2048 total, staggered
}

extern "C" void kernel_launch(void* const* d_in, const int* in_sizes, int n_in,
                              void* d_out, int out_size, void* d_ws, size_t ws_size,
                              hipStream_t stream) {
    const float* pred = (const float*)d_in[0];   // (256,133,1024) fp32
    const float* kpts = (const float*)d_in[1];   // (256,133,3) fp32
    float* out = (float*)d_out;

    hipMemsetAsync(out, 0, sizeof(float), stream);
    rtmcc_kernel<<<NBLOCKS, 256, 0, stream>>>(pred, kpts, out);
}

// Round 11
// 25.753 us; speedup vs baseline: 1.7021x; 1.7021x over previous
//
#include <hip/hip_runtime.h>
#include <math.h>

#define NKP 133
#define NROWS (256 * NKP)            // 34048 rows of 1024
#define RH_TOTAL (2 * NROWS)         // 68096 row-halves of 512
#define NQUADS (RH_TOTAL / 4)        // 17024 quads (4 row-halves each)
#define NBLOCKS 2048
#define NWAVES (NBLOCKS * 4)         // 8192: ~2.08 quads/wave
#define C2P  14.4269504088896f       // 10*log2(e): exp(10x)=exp2(C2P*x)
#define NK2  0.02251706f             // log2(e)/(2*5.66^2)
#define RAD  16.98f                  // 5.66*3
#define LN2f 0.69314718055994531f
#define WTAPS 5                      // 80-wide window covers |d|<=35 in all clamp cases

static __device__ __forceinline__ float fexp2(float x) { return __builtin_amdgcn_exp2f(x); }
static __device__ __forceinline__ float frcp (float x) { return __builtin_amdgcn_rcpf(x); }

__global__ __launch_bounds__(256) void rtmcc_partial_kernel(
    const float* __restrict__ pred,       // [RH_TOTAL][512]
    const float* __restrict__ keypoints,  // [NROWS][3]
    float* __restrict__ partials)         // [NBLOCKS]
{
    const int wave = threadIdx.x >> 6;
    const int lane = threadIdx.x & 63;
    const int g    = lane >> 4;           // 16-lane group -> one row-half
    const int l4   = lane & 15;
    const int gh   = g >> 1;              // row within quad pair
    const int h    = g & 1;               // half: 0=x, 1=y
    __shared__ float2 twb[256];           // (e-1, e*g) at d=t-128; zero |d|>35
    __shared__ float lds[4];

    int q = blockIdx.x * 4 + wave;        // first quad for this wave

    // rolling keypoint prefetch — issued before table build, latency hidden
    float kx, ky, kv;
    {
        const int row = 2 * q + gh;
        kx = keypoints[row * 3 + 0];
        ky = keypoints[row * 3 + 1];
        kv = keypoints[row * 3 + 2];
    }

    {   // window table once per block
        const int t = threadIdx.x;
        const float d = (float)(t - 128);
        float em1 = 0.0f, eg = 0.0f;
        if (fabsf(d) <= 35.0f) {
            const float gg = fexp2(-d * d * NK2);   // gaussian target
            const float e  = fexp2(gg * C2P);       // exp(10*g)
            em1 = e - 1.0f; eg = e * gg;
        }
        twb[t] = make_float2(em1, eg);
    }
    __syncthreads();

    float acc = 0.0f;

    for (; q < NQUADS; q += NWAVES) {
        const float kxc = kx, kyc = ky, kvc = kv;
        const int qn = q + NWAVES;
        if (qn < NQUADS) {                // prefetch next iteration's keypoints
            const int rown = 2 * qn + gh;
            kx = keypoints[rown * 3 + 0];
            ky = keypoints[rown * 3 + 1];
            kv = keypoints[rown * 3 + 2];
        }

        const float mux = rintf(kxc * 2.0f);    // half-to-even = jnp.round
        const float muy = rintf(kyc * 2.0f);
        const bool oob = (mux - RAD >= 512.0f) || (muy - RAD >= 512.0f) ||
                         (mux + RAD + 1.0f < 0.0f) || (muy + RAD + 1.0f < 0.0f);
        const bool visible = (kvc >= 0.5f);
        const float w = (visible && oob) ? 0.0f : kvc;
        const bool act = (w > 0.0f);            // uniform within 16-lane group

        float S = 0.0f, Zw = 0.0f, R = 0.0f;
        if (act) {
            const float* ph = pred + (size_t)(4 * q + g) * 512;

            // ---- bulk: 8 float4 loads, column-interleaved (coalesced) ----
            float4 qv[8];
            #pragma unroll
            for (int v = 0; v < 8; ++v)
                qv[v] = *reinterpret_cast<const float4*>(ph + v * 64 + l4 * 4);

            float s0 = 0.f, s1 = 0.f, r0 = 0.f, r1 = 0.f;   // dual chains
            #pragma unroll
            for (int v = 0; v < 8; v += 2) {
                s0 += fexp2(C2P*qv[v].x)   + fexp2(C2P*qv[v].y)
                    + fexp2(C2P*qv[v].z)   + fexp2(C2P*qv[v].w);
                r0 -= (qv[v].x + qv[v].y) + (qv[v].z + qv[v].w);
                s1 += fexp2(C2P*qv[v+1].x) + fexp2(C2P*qv[v+1].y)
                    + fexp2(C2P*qv[v+1].z) + fexp2(C2P*qv[v+1].w);
                r1 -= (qv[v+1].x + qv[v+1].y) + (qv[v+1].z + qv[v+1].w);
            }
            S = s0 + s1; R = r0 + r1;

            // ---- window: 80 elems around mu, 5/lane, LDS table lookups ----
            // t = idx - mui + 128 provably in [48,208) for all mui in [0,512]
            const float mu = h ? muy : mux;
            const int mui = (int)mu;
            int ws = mui - 40; ws = ws < 0 ? 0 : (ws > 432 ? 432 : ws);
            #pragma unroll
            for (int v = 0; v < WTAPS; ++v) {
                const int idx = ws + l4 + v * 16;        // [ws, ws+80)
                const float pw = ph[idx];                // cache-hot re-read
                const float2 te = twb[idx - mui + 128];  // ds_read_b64, no clamp
                Zw += te.x;
                R  += te.y - te.x * pw;
            }
        }

        // ---- 4-step butterfly within each 16-lane group ----
        #pragma unroll
        for (int off = 1; off < 16; off <<= 1) {
            S  += __shfl_xor(S,  off, 64);
            Zw += __shfl_xor(Zw, off, 64);
            R  += __shfl_xor(R,  off, 64);
        }

        if (act) {
            const float Z = 512.0f + Zw;        // far-field e == 1.0f exactly
            acc += w * (10.0f * R * frcp(Z) + (__log2f(S) - __log2f(Z)) * LN2f);
        }
    }

    // each group's loss sits in all 16 of its lanes -> /16 exact
    acc *= (1.0f / (16.0f * 512.0f * 133.0f));
    #pragma unroll
    for (int off = 1; off < 64; off <<= 1) acc += __shfl_xor(acc, off, 64);
    if (lane == 0) lds[wave] = acc;
    __syncthreads();
    if (threadIdx.x == 0)
        partials[blockIdx.x] = lds[0] + lds[1] + lds[2] + lds[3];
}

__global__ __launch_bounds__(256) void rtmcc_reduce_kernel(
    const float* __restrict__ partials, float* __restrict__ out)
{
    __shared__ float lds[4];
    float s = 0.0f;
    for (int i = threadIdx.x; i < NBLOCKS; i += 256) s += partials[i];
    #pragma unroll
    for (int off = 1; off < 64; off <<= 1) s += __shfl_xor(s, off, 64);
    if ((threadIdx.x & 63) == 0) lds[threadIdx.x >> 6] = s;
    __syncthreads();
    if (threadIdx.x == 0) out[0] = lds[0] + lds[1] + lds[2] + lds[3];
}

extern "C" void kernel_launch(void* const* d_in, const int* in_sizes, int n_in,
                              void* d_out, int out_size, void* d_ws, size_t ws_size,
                              hipStream_t stream) {
    const float* pred = (const float*)d_in[0];   // (256,133,1024) fp32
    const float* kpts = (const float*)d_in[1];   // (256,133,3) fp32
    float* out = (float*)d_out;
    float* partials = (float*)d_ws;

    rtmcc_partial_kernel<<<NBLOCKS, 256, 0, stream>>>(pred, kpts, partials);
    rtmcc_reduce_kernel<<<1, 256, 0, stream>>>(partials, out);
}

// Round 12
// 24.589 us; speedup vs baseline: 1.7826x; 1.0473x over previous
//
#include <hip/hip_runtime.h>
#include <math.h>

#define NKP 133
#define NROWS (256 * NKP)            // 34048 rows of 1024
#define RH_TOTAL (2 * NROWS)         // 68096 row-halves of 512
#define NQUADS (RH_TOTAL / 4)        // 17024 quads (4 row-halves each)
#define NBLOCKS 2048
#define NWAVES (NBLOCKS * 4)         // 8192: ~2.08 quads/wave
#define C2P  14.4269504088896f       // 10*log2(e): exp(10x)=exp2(C2P*x)
#define NK2  0.02251706f             // log2(e)/(2*5.66^2)
#define RAD  16.98f                  // 5.66*3
#define LN2f 0.69314718055994531f
#define WTAPS 5                      // 80-wide window covers |d|<=35 in all clamp cases

static __device__ __forceinline__ float fexp2(float x) { return __builtin_amdgcn_exp2f(x); }
static __device__ __forceinline__ float frcp (float x) { return __builtin_amdgcn_rcpf(x); }

__global__ __launch_bounds__(256) void rtmcc_partial_kernel(
    const float* __restrict__ pred,       // [RH_TOTAL][512]
    const float* __restrict__ keypoints,  // [NROWS][3]
    float* __restrict__ partials)         // [NBLOCKS]
{
    const int wave = threadIdx.x >> 6;
    const int lane = threadIdx.x & 63;
    const int g    = lane >> 4;           // 16-lane group -> one row-half
    const int l4   = lane & 15;
    const int gh   = g >> 1;              // row within quad pair
    const int h    = g & 1;               // half: 0=x, 1=y
    __shared__ float2 twb[256];           // (e-1, e*g) at d=t-128; zero |d|>35
    __shared__ float lds[4];

    int q = blockIdx.x * 4 + wave;        // first quad for this wave

    // rolling keypoint prefetch — issued before table build, latency hidden
    float kx, ky, kv;
    {
        const int row = 2 * q + gh;
        kx = keypoints[row * 3 + 0];
        ky = keypoints[row * 3 + 1];
        kv = keypoints[row * 3 + 2];
    }

    {   // window table once per block
        const int t = threadIdx.x;
        const float d = (float)(t - 128);
        float em1 = 0.0f, eg = 0.0f;
        if (fabsf(d) <= 35.0f) {
            const float gg = fexp2(-d * d * NK2);   // gaussian target
            const float e  = fexp2(gg * C2P);       // exp(10*g)
            em1 = e - 1.0f; eg = e * gg;
        }
        twb[t] = make_float2(em1, eg);
    }
    __syncthreads();

    float acc = 0.0f;

    for (; q < NQUADS; q += NWAVES) {
        const float kxc = kx, kyc = ky, kvc = kv;
        const int qn = q + NWAVES;
        if (qn < NQUADS) {                // prefetch next iteration's keypoints
            const int rown = 2 * qn + gh;
            kx = keypoints[rown * 3 + 0];
            ky = keypoints[rown * 3 + 1];
            kv = keypoints[rown * 3 + 2];
        }

        const float mux = rintf(kxc * 2.0f);    // half-to-even = jnp.round
        const float muy = rintf(kyc * 2.0f);
        const bool oob = (mux - RAD >= 512.0f) || (muy - RAD >= 512.0f) ||
                         (mux + RAD + 1.0f < 0.0f) || (muy + RAD + 1.0f < 0.0f);
        const bool visible = (kvc >= 0.5f);
        const float w = (visible && oob) ? 0.0f : kvc;
        const bool act = (w > 0.0f);            // uniform within 16-lane group

        float S = 0.0f, Zw = 0.0f, R = 0.0f;
        if (act) {
            const float* ph = pred + (size_t)(4 * q + g) * 512;

            // ---- bulk in two register-lean batches of 4 float4.
            //      Batch-B loads issue before batch-A is consumed (MLP kept),
            //      but only ~4 float4 live at once -> lower peak VGPR. ----
            float4 qa0, qa1, qa2, qa3, qb0, qb1, qb2, qb3;
            qa0 = *reinterpret_cast<const float4*>(ph +   0 + l4 * 4);
            qa1 = *reinterpret_cast<const float4*>(ph +  64 + l4 * 4);
            qa2 = *reinterpret_cast<const float4*>(ph + 128 + l4 * 4);
            qa3 = *reinterpret_cast<const float4*>(ph + 192 + l4 * 4);
            qb0 = *reinterpret_cast<const float4*>(ph + 256 + l4 * 4);
            qb1 = *reinterpret_cast<const float4*>(ph + 320 + l4 * 4);
            qb2 = *reinterpret_cast<const float4*>(ph + 384 + l4 * 4);
            qb3 = *reinterpret_cast<const float4*>(ph + 448 + l4 * 4);

            float s0 = 0.f, s1 = 0.f, r0 = 0.f, r1 = 0.f;   // dual chains
#define BULK4(Q0, Q1)                                                          \
            s0 += fexp2(C2P*Q0.x) + fexp2(C2P*Q0.y)                            \
                + fexp2(C2P*Q0.z) + fexp2(C2P*Q0.w);                           \
            r0 -= (Q0.x + Q0.y) + (Q0.z + Q0.w);                               \
            s1 += fexp2(C2P*Q1.x) + fexp2(C2P*Q1.y)                            \
                + fexp2(C2P*Q1.z) + fexp2(C2P*Q1.w);                           \
            r1 -= (Q1.x + Q1.y) + (Q1.z + Q1.w);
            BULK4(qa0, qa1)
            BULK4(qa2, qa3)
            BULK4(qb0, qb1)
            BULK4(qb2, qb3)
#undef BULK4
            S = s0 + s1; R = r0 + r1;

            // ---- window: 80 elems around mu, 5/lane, LDS table lookups ----
            // t = idx - mui + 128 provably in [48,208) for all mui in [0,512]
            const float mu = h ? muy : mux;
            const int mui = (int)mu;
            int ws = mui - 40; ws = ws < 0 ? 0 : (ws > 432 ? 432 : ws);
            #pragma unroll
            for (int v = 0; v < WTAPS; ++v) {
                const int idx = ws + l4 + v * 16;        // [ws, ws+80)
                const float pw = ph[idx];                // cache-hot re-read
                const float2 te = twb[idx - mui + 128];  // ds_read_b64, no clamp
                Zw += te.x;
                R  += te.y - te.x * pw;
            }
        }

        // ---- 4-step butterfly within each 16-lane group ----
        #pragma unroll
        for (int off = 1; off < 16; off <<= 1) {
            S  += __shfl_xor(S,  off, 64);
            Zw += __shfl_xor(Zw, off, 64);
            R  += __shfl_xor(R,  off, 64);
        }

        if (act) {
            const float Z = 512.0f + Zw;        // far-field e == 1.0f exactly
            acc += w * (10.0f * R * frcp(Z) + (__log2f(S) - __log2f(Z)) * LN2f);
        }
    }

    // each group's loss sits in all 16 of its lanes -> /16 exact
    acc *= (1.0f / (16.0f * 512.0f * 133.0f));
    #pragma unroll
    for (int off = 1; off < 64; off <<= 1) acc += __shfl_xor(acc, off, 64);
    if (lane == 0) lds[wave] = acc;
    __syncthreads();
    if (threadIdx.x == 0)
        partials[blockIdx.x] = lds[0] + lds[1] + lds[2] + lds[3];
}

__global__ __launch_bounds__(64) void rtmcc_reduce_kernel(
    const float* __restrict__ partials, float* __restrict__ out)
{
    float s = 0.0f;
    #pragma unroll
    for (int i = 0; i < NBLOCKS / 64; ++i) s += partials[i * 64 + threadIdx.x];
    #pragma unroll
    for (int off = 1; off < 64; off <<= 1) s += __shfl_xor(s, off, 64);
    if (threadIdx.x == 0) out[0] = s;
}

extern "C" void kernel_launch(void* const* d_in, const int* in_sizes, int n_in,
                              void* d_out, int out_size, void* d_ws, size_t ws_size,
                              hipStream_t stream) {
    const float* pred = (const float*)d_in[0];   // (256,133,1024) fp32
    const float* kpts = (const float*)d_in[1];   // (256,133,3) fp32
    float* out = (float*)d_out;
    float* partials = (float*)d_ws;

    rtmcc_partial_kernel<<<NBLOCKS, 256, 0, stream>>>(pred, kpts, partials);
    rtmcc_reduce_kernel<<<1, 64, 0, stream>>>(partials, out);
}